// Round 9
// baseline (2383.630 us; speedup 1.0000x reference)
//
#include <hip/hip_runtime.h>

// ---------------------------------------------------------------------------
// MusicLSTM: B=256, T=2048, I=2, H=128 (4H=512 gates), P=129 pitches.
//   prep_k  : note_W+dur_W -> f16 Wn[144][128] in ws
//   lstm4_k : 1 WG (256 thr, 4 waves = 1/SIMD) per batch. gates[512] =
//             W_hh . h via MFMA 16x16x32, h broadcast as A (all rows equal).
//             Wave w owns n-tiles {w+4s, s=0..7}: lane (p,q) gets
//             col j = 16w + 64*(q>>1) + p, gates G[tt] = acc[(q>>1)+2tt][0].
//             One cell update per lane; writers are q&1==0 lanes. One raw
//             s_barrier per step (lgkm-only drain; global hs stores stay in
//             flight). Incremental hs store addressing (no 64-bit mul in
//             loop). h double-buffered in LDS; x staged in 128-step chunks.
//   proj_k  : MFMA f16 GEMM over hs -> note/dur logits, masked rows zeroed.
// Fragment layout conventions (verified by the passing proj_k):
//   A: lane l holds A[m=l&15][k=32*kt+8*(l>>4)+e], e=0..7
//   B: lane l holds B[n=l&15][k=32*kt+8*(l>>4)+e]
//   D: lane l reg r holds D[m=(l>>4)*4+r][n=l&15]
// ---------------------------------------------------------------------------

typedef _Float16 f16;
typedef _Float16 f16x8 __attribute__((ext_vector_type(8)));
typedef float    f32x4 __attribute__((ext_vector_type(4)));

#define B_  256
#define T_  2048
#define H_  128
#define P_  129

static constexpr size_t NOTE_N   = (size_t)B_ * T_ * P_;
static constexpr size_t DUR_BASE = NOTE_N;
static constexpr size_t HT_BASE  = DUR_BASE + (size_t)B_ * T_;
static constexpr size_t CT_BASE  = HT_BASE + (size_t)B_ * H_;

#if defined(__has_builtin)
#if __has_builtin(__builtin_amdgcn_exp2f)
#define EXP2F(x) __builtin_amdgcn_exp2f(x)
#endif
#endif
#ifndef EXP2F
#define EXP2F(x) __expf((x) * 0.6931471805599453f)
#endif

__device__ __forceinline__ float fast_rcp(float x) { return __builtin_amdgcn_rcpf(x); }

__device__ __forceinline__ float sigmoid_f(float x) {
    float e = EXP2F(-1.44269504f * x);
    return fast_rcp(1.f + e);
}
__device__ __forceinline__ float tanh_f(float x) {
    float e = EXP2F(2.885390082f * x);
    return (e - 1.f) * fast_rcp(e + 1.f);
}

// hs row bt lives at the front of note row bt, rounded up to 16B alignment.
__device__ __forceinline__ f16* hs_row(float* out, int bt) {
    size_t byteoff = ((size_t)bt * (P_ * 4) + 15) & ~(size_t)15;
    return (f16*)((char*)out + byteoff);
}

// ---------------------------------------------------------------------------
__global__ __launch_bounds__(256) void prep_k(const float* __restrict__ note_W,
                                              const float* __restrict__ dur_W,
                                              f16* __restrict__ Wn) {
    int i = threadIdx.x + blockIdx.x * 256;
    if (i >= 144 * 128) return;
    int row = i >> 7, k = i & 127;
    float v = 0.f;
    if (row < 129)       v = note_W[row * 128 + k];
    else if (row == 129) v = dur_W[k];
    Wn[i] = (f16)v;
}

// ---------------------------------------------------------------------------
__global__ __launch_bounds__(256, 1) void lstm4_k(const float* __restrict__ x,
                                                  const int* __restrict__ lengths,
                                                  const float* __restrict__ W_ih,
                                                  const float* __restrict__ W_hh,
                                                  float* __restrict__ out) {
    __shared__ __align__(16) f16 h_sh[2][H_];   // double-buffered h (512 B)
    __shared__ __align__(8) float2 xs[128];     // x chunk: 128 steps (1 KB)

    const int tid = threadIdx.x;
    const int b = blockIdx.x;
    const int w = tid >> 6;       // wave 0..3 (one per SIMD)
    const int l = tid & 63;
    const int p = l & 15;
    const int q = l >> 4;
    const int sel = q >> 1;                    // 0: col j=16w+p, 1: j=16w+64+p
    const int j = 16 * w + 64 * sel + p;       // this lane's hidden column
    const bool writer = ((q & 1) == 0);

    // B-fragments: 8 gate-row groups nt = w+4s; global row c = 16*nt + p.
    // (s = 2*tt + sel maps to gate tt of this lane's column.)
    f16x8 Bf[8][4];
    float wxx[8], wxy[8];
#pragma unroll
    for (int s = 0; s < 8; s++) {
        const int c = 16 * (w + 4 * s) + p;
        const float* wr = W_hh + (size_t)c * H_ + 8 * q;
#pragma unroll
        for (int kt = 0; kt < 4; kt++) {
            float4 v1 = *(const float4*)(wr + 32 * kt);
            float4 v2 = *(const float4*)(wr + 32 * kt + 4);
            f16x8 f;
            f[0] = (f16)v1.x; f[1] = (f16)v1.y; f[2] = (f16)v1.z; f[3] = (f16)v1.w;
            f[4] = (f16)v2.x; f[5] = (f16)v2.y; f[6] = (f16)v2.z; f[7] = (f16)v2.w;
            Bf[s][kt] = f;
        }
        wxx[s] = W_ih[2 * c];
        wxy[s] = W_ih[2 * c + 1];
    }
    const int len = lengths[b];
    if (tid < 2 * H_) ((f16*)h_sh)[tid] = (f16)0.f;

    // incremental hs store pointer (row stride pattern 528,512,512,512)
    char* hp = (char*)out + (size_t)b * (T_ * 516ULL) + 2 * j;

    float c_reg = 0.f, h_reg = 0.f;

    for (int t = 0; t < len; t++) {
        if ((t & 127) == 0) {
            // refill x chunk [t, t+128). Full drain barrier, amortized /128.
            __syncthreads();
            if (tid < 128)
                xs[tid] = *(const float2*)(x + (size_t)b * T_ * 2 + (size_t)(t + tid) * 2);
            __syncthreads();
        }
        const int cur = t & 1;

        // A-fragments: h broadcast (same 16B for all lanes of a q-group)
        f16x8 Af[4];
#pragma unroll
        for (int kt = 0; kt < 4; kt++)
            Af[kt] = *(const f16x8*)(&h_sh[cur][32 * kt + 8 * q]);

        f32x4 acc[8];
#pragma unroll
        for (int s = 0; s < 8; s++) acc[s] = f32x4{0.f, 0.f, 0.f, 0.f};
#pragma unroll
        for (int kt = 0; kt < 4; kt++) {
#pragma unroll
            for (int s = 0; s < 8; s++)
                acc[s] = __builtin_amdgcn_mfma_f32_16x16x32_f16(
                    Af[kt], Bf[s][kt], acc[s], 0, 0, 0);
        }

        const float2 xv = xs[t & 127];
        float G[4];
#pragma unroll
        for (int tt = 0; tt < 4; tt++) {
            const int s = sel + 2 * tt;
            G[tt] = acc[s][0] + __builtin_fmaf(wxy[s], xv.y, wxx[s] * xv.x);
        }

        const float ig = sigmoid_f(G[0]);
        const float fg = sigmoid_f(G[1]);
        const float gg = tanh_f(G[2]);
        const float og = sigmoid_f(G[3]);
        c_reg = __builtin_fmaf(fg, c_reg, ig * gg);
        h_reg = og * tanh_f(fminf(fmaxf(c_reg, -15.f), 15.f));

        if (writer) {
            const f16 h16 = (f16)h_reg;
            h_sh[cur ^ 1][j] = h16;     // LDS (lgkm)
            *(f16*)hp = h16;            // global, stays in flight
        }
        hp += 512 + (((t & 3) == 0) ? 16 : 0);

        // drain LDS only; global hs stores remain outstanding
        asm volatile("s_waitcnt lgkmcnt(0)" ::: "memory");
        __builtin_amdgcn_sched_barrier(0);
        __builtin_amdgcn_s_barrier();
        __builtin_amdgcn_sched_barrier(0);
    }

    if (writer) {
        out[HT_BASE + (size_t)b * H_ + j] = h_reg;
        out[CT_BASE + (size_t)b * H_ + j] = c_reg;
    }
}

// ---------------------------------------------------------------------------
// Projection GEMM: C[bt, n] = hs[bt,:] . Wn[n,:] + bias, masked by t<len.
__global__ __launch_bounds__(256) void proj_k(const int* __restrict__ lengths,
                                              const f16* __restrict__ Wn,
                                              const float* __restrict__ note_b,
                                              const float* __restrict__ dur_b,
                                              float* __restrict__ out) {
    __shared__ __align__(16) f16 wn_sh[144 * 136];

    const int tid = threadIdx.x;
    {
        unsigned int* dst = (unsigned int*)wn_sh;
        const unsigned int* src = (const unsigned int*)Wn;
        for (int w = tid; w < 144 * 64; w += 256) {
            int row = w >> 6, cw = w & 63;
            dst[row * 68 + cw] = src[w];
        }
    }
    __syncthreads();

    const int wv = tid >> 6;
    const int l = tid & 63;
    const int tile = blockIdx.x * 4 + wv;
    const int bt0 = tile * 16;
    const int b = bt0 >> 11;
    const int t0 = bt0 & 2047;
    const int len = lengths[b];
    const int r16 = l & 15, q = l >> 4;

    f32x4 acc[9];
#pragma unroll
    for (int nf = 0; nf < 9; nf++) acc[nf] = f32x4{0.f, 0.f, 0.f, 0.f};

    const bool live = (t0 < len);
    if (live) {
        f16x8 a[4];
        {
            const f16* ar = hs_row(out, bt0 + r16);
#pragma unroll
            for (int kk = 0; kk < 4; kk++)
                a[kk] = *(const f16x8*)(ar + kk * 32 + q * 8);
        }
#pragma unroll
        for (int nf = 0; nf < 9; nf++) {
            const f16* brow = wn_sh + (nf * 16 + r16) * 136 + q * 8;
#pragma unroll
            for (int kk = 0; kk < 4; kk++) {
                f16x8 bb = *(const f16x8*)(brow + kk * 32);
                acc[nf] = __builtin_amdgcn_mfma_f32_16x16x32_f16(a[kk], bb, acc[nf], 0, 0, 0);
            }
        }
    }

#pragma unroll
    for (int nf = 0; nf < 9; nf++) {
        int col = nf * 16 + r16;
        float bias = 0.f;
        if (col < 129)       bias = note_b[col];
        else if (col == 129) bias = dur_b[0];
#pragma unroll
        for (int r = 0; r < 4; r++) {
            int rowbt = bt0 + q * 4 + r;
            int t = t0 + q * 4 + r;
            float v = (t < len) ? (acc[nf][r] + bias) : 0.f;
            if (col < 129)
                out[(size_t)rowbt * P_ + col] = v;
            else if (col == 129)
                out[DUR_BASE + rowbt] = v;
        }
    }
}

// ---------------------------------------------------------------------------
extern "C" void kernel_launch(void* const* d_in, const int* in_sizes, int n_in,
                              void* d_out, int out_size, void* d_ws, size_t ws_size,
                              hipStream_t stream) {
    const float* x       = (const float*)d_in[0];
    const int*   lengths = (const int*)d_in[1];
    const float* W_ih    = (const float*)d_in[2];
    const float* W_hh    = (const float*)d_in[3];
    const float* note_W  = (const float*)d_in[4];
    const float* note_b  = (const float*)d_in[5];
    const float* dur_W   = (const float*)d_in[6];
    const float* dur_b   = (const float*)d_in[7];
    float* out = (float*)d_out;
    f16* Wn = (f16*)d_ws;

    prep_k<<<72, 256, 0, stream>>>(note_W, dur_W, Wn);
    lstm4_k<<<B_, 256, 0, stream>>>(x, lengths, W_ih, W_hh, out);
    proj_k<<<(B_ * T_) / 64, 256, 0, stream>>>(lengths, Wn, note_b, dur_b, out);
}

// Round 10
// 1031.076 us; speedup vs baseline: 2.3118x; 2.3118x over previous
//
#include <hip/hip_runtime.h>

// ---------------------------------------------------------------------------
// MusicLSTM: B=256, T=2048, I=2, H=128 (4H=512 gates), P=129 pitches.
//   prep_k  : note_W+dur_W -> f16 Wn[144][128] in ws
//   lstm4_k : 1 WG (256 thr, 4 waves = 1/SIMD) per batch. gates[512] =
//             W_hh . h via MFMA 16x16x32, h broadcast as A (all rows equal).
//             Wave w owns n-tiles {w+4s, s=0..7}: lane (p,q) gets
//             col j = 16w + 64*(q>>1) + p; gate tt of that column lives in
//             acc[2tt + (q>>1)][0]. r9 BUG FIX: acc/wxx were indexed with the
//             RUNTIME s=sel+2tt -> whole acc array demoted to scratch (rule
//             #20; VGPR fell to 144, 2.3x slowdown). Now: static indices
//             acc[2tt][0] / acc[2tt+1][0] + v_cndmask select. Zero-init of
//             acc folded into the kt=0 MFMA (C = hoisted zero quad).
//             One raw s_barrier per step (lgkm-only drain; global hs stores
//             stay in flight). Incremental hs store addressing. h
//             double-buffered in LDS; x staged in 128-step chunks.
//   proj_k  : MFMA f16 GEMM over hs -> note/dur logits, masked rows zeroed.
// Fragment layout conventions (verified by the passing proj_k):
//   A: lane l holds A[m=l&15][k=32*kt+8*(l>>4)+e], e=0..7
//   B: lane l holds B[n=l&15][k=32*kt+8*(l>>4)+e]
//   D: lane l reg r holds D[m=(l>>4)*4+r][n=l&15]
// ---------------------------------------------------------------------------

typedef _Float16 f16;
typedef _Float16 f16x8 __attribute__((ext_vector_type(8)));
typedef float    f32x4 __attribute__((ext_vector_type(4)));

#define B_  256
#define T_  2048
#define H_  128
#define P_  129

static constexpr size_t NOTE_N   = (size_t)B_ * T_ * P_;
static constexpr size_t DUR_BASE = NOTE_N;
static constexpr size_t HT_BASE  = DUR_BASE + (size_t)B_ * T_;
static constexpr size_t CT_BASE  = HT_BASE + (size_t)B_ * H_;

#if defined(__has_builtin)
#if __has_builtin(__builtin_amdgcn_exp2f)
#define EXP2F(x) __builtin_amdgcn_exp2f(x)
#endif
#endif
#ifndef EXP2F
#define EXP2F(x) __expf((x) * 0.6931471805599453f)
#endif

__device__ __forceinline__ float fast_rcp(float x) { return __builtin_amdgcn_rcpf(x); }

__device__ __forceinline__ float sigmoid_f(float x) {
    float e = EXP2F(-1.44269504f * x);
    return fast_rcp(1.f + e);
}
__device__ __forceinline__ float tanh_f(float x) {
    float e = EXP2F(2.885390082f * x);
    return (e - 1.f) * fast_rcp(e + 1.f);
}

// hs row bt lives at the front of note row bt, rounded up to 16B alignment.
__device__ __forceinline__ f16* hs_row(float* out, int bt) {
    size_t byteoff = ((size_t)bt * (P_ * 4) + 15) & ~(size_t)15;
    return (f16*)((char*)out + byteoff);
}

// ---------------------------------------------------------------------------
__global__ __launch_bounds__(256) void prep_k(const float* __restrict__ note_W,
                                              const float* __restrict__ dur_W,
                                              f16* __restrict__ Wn) {
    int i = threadIdx.x + blockIdx.x * 256;
    if (i >= 144 * 128) return;
    int row = i >> 7, k = i & 127;
    float v = 0.f;
    if (row < 129)       v = note_W[row * 128 + k];
    else if (row == 129) v = dur_W[k];
    Wn[i] = (f16)v;
}

// ---------------------------------------------------------------------------
__global__ __launch_bounds__(256, 1) void lstm4_k(const float* __restrict__ x,
                                                  const int* __restrict__ lengths,
                                                  const float* __restrict__ W_ih,
                                                  const float* __restrict__ W_hh,
                                                  float* __restrict__ out) {
    __shared__ __align__(16) f16 h_sh[2][H_];   // double-buffered h (512 B)
    __shared__ __align__(8) float2 xs[128];     // x chunk: 128 steps (1 KB)

    const int tid = threadIdx.x;
    const int b = blockIdx.x;
    const int w = tid >> 6;       // wave 0..3 (one per SIMD)
    const int l = tid & 63;
    const int p = l & 15;
    const int q = l >> 4;
    const int sel = q >> 1;                    // 0: col j=16w+p, 1: j=16w+64+p
    const int j = 16 * w + 64 * sel + p;       // this lane's hidden column
    const bool writer = ((q & 1) == 0);

    // B-fragments: 8 gate-row groups nt = w+4s; global row c = 16*nt + p.
    // (s = 2*tt + sel maps to gate tt of this lane's column.)
    f16x8 Bf[8][4];
    float wxx[8], wxy[8];
#pragma unroll
    for (int s = 0; s < 8; s++) {
        const int c = 16 * (w + 4 * s) + p;
        const float* wr = W_hh + (size_t)c * H_ + 8 * q;
#pragma unroll
        for (int kt = 0; kt < 4; kt++) {
            float4 v1 = *(const float4*)(wr + 32 * kt);
            float4 v2 = *(const float4*)(wr + 32 * kt + 4);
            f16x8 f;
            f[0] = (f16)v1.x; f[1] = (f16)v1.y; f[2] = (f16)v1.z; f[3] = (f16)v1.w;
            f[4] = (f16)v2.x; f[5] = (f16)v2.y; f[6] = (f16)v2.z; f[7] = (f16)v2.w;
            Bf[s][kt] = f;
        }
        wxx[s] = W_ih[2 * c];
        wxy[s] = W_ih[2 * c + 1];
    }
    const int len = lengths[b];
    if (tid < 2 * H_) ((f16*)h_sh)[tid] = (f16)0.f;

    // incremental hs store pointer (row stride pattern 528,512,512,512)
    char* hp = (char*)out + (size_t)b * (T_ * 516ULL) + 2 * j;

    const f32x4 z4 = {0.f, 0.f, 0.f, 0.f};
    float c_reg = 0.f, h_reg = 0.f;

    for (int t = 0; t < len; t++) {
        if ((t & 127) == 0) {
            // refill x chunk [t, t+128). Full drain barrier, amortized /128.
            __syncthreads();
            if (tid < 128)
                xs[tid] = *(const float2*)(x + (size_t)b * T_ * 2 + (size_t)(t + tid) * 2);
            __syncthreads();
        }
        const int cur = t & 1;

        // A-fragments: h broadcast (same 16B for all lanes of a q-group)
        f16x8 Af[4];
#pragma unroll
        for (int kt = 0; kt < 4; kt++)
            Af[kt] = *(const f16x8*)(&h_sh[cur][32 * kt + 8 * q]);

        f32x4 acc[8];
#pragma unroll
        for (int s = 0; s < 8; s++)
            acc[s] = __builtin_amdgcn_mfma_f32_16x16x32_f16(Af[0], Bf[s][0], z4, 0, 0, 0);
#pragma unroll
        for (int kt = 1; kt < 4; kt++) {
#pragma unroll
            for (int s = 0; s < 8; s++)
                acc[s] = __builtin_amdgcn_mfma_f32_16x16x32_f16(
                    Af[kt], Bf[s][kt], acc[s], 0, 0, 0);
        }

        const float2 xv = xs[t & 127];
        // STATIC acc indices; lane's column selected via cndmask (rule #20)
        float G[4];
#pragma unroll
        for (int tt = 0; tt < 4; tt++) {
            float ga = acc[2 * tt][0] +
                       __builtin_fmaf(wxy[2 * tt], xv.y, wxx[2 * tt] * xv.x);
            float gb = acc[2 * tt + 1][0] +
                       __builtin_fmaf(wxy[2 * tt + 1], xv.y, wxx[2 * tt + 1] * xv.x);
            G[tt] = sel ? gb : ga;
        }

        const float ig = sigmoid_f(G[0]);
        const float fg = sigmoid_f(G[1]);
        const float gg = tanh_f(G[2]);
        const float og = sigmoid_f(G[3]);
        c_reg = __builtin_fmaf(fg, c_reg, ig * gg);
        h_reg = og * tanh_f(fminf(fmaxf(c_reg, -15.f), 15.f));

        if (writer) {
            const f16 h16 = (f16)h_reg;
            h_sh[cur ^ 1][j] = h16;     // LDS (lgkm)
            *(f16*)hp = h16;            // global, stays in flight
        }
        hp += 512 + (((t & 3) == 0) ? 16 : 0);

        // drain LDS only; global hs stores remain outstanding
        asm volatile("s_waitcnt lgkmcnt(0)" ::: "memory");
        __builtin_amdgcn_sched_barrier(0);
        __builtin_amdgcn_s_barrier();
        __builtin_amdgcn_sched_barrier(0);
    }

    if (writer) {
        out[HT_BASE + (size_t)b * H_ + j] = h_reg;
        out[CT_BASE + (size_t)b * H_ + j] = c_reg;
    }
}

// ---------------------------------------------------------------------------
// Projection GEMM: C[bt, n] = hs[bt,:] . Wn[n,:] + bias, masked by t<len.
__global__ __launch_bounds__(256) void proj_k(const int* __restrict__ lengths,
                                              const f16* __restrict__ Wn,
                                              const float* __restrict__ note_b,
                                              const float* __restrict__ dur_b,
                                              float* __restrict__ out) {
    __shared__ __align__(16) f16 wn_sh[144 * 136];

    const int tid = threadIdx.x;
    {
        unsigned int* dst = (unsigned int*)wn_sh;
        const unsigned int* src = (const unsigned int*)Wn;
        for (int w = tid; w < 144 * 64; w += 256) {
            int row = w >> 6, cw = w & 63;
            dst[row * 68 + cw] = src[w];
        }
    }
    __syncthreads();

    const int wv = tid >> 6;
    const int l = tid & 63;
    const int tile = blockIdx.x * 4 + wv;
    const int bt0 = tile * 16;
    const int b = bt0 >> 11;
    const int t0 = bt0 & 2047;
    const int len = lengths[b];
    const int r16 = l & 15, q = l >> 4;

    f32x4 acc[9];
#pragma unroll
    for (int nf = 0; nf < 9; nf++) acc[nf] = f32x4{0.f, 0.f, 0.f, 0.f};

    const bool live = (t0 < len);
    if (live) {
        f16x8 a[4];
        {
            const f16* ar = hs_row(out, bt0 + r16);
#pragma unroll
            for (int kk = 0; kk < 4; kk++)
                a[kk] = *(const f16x8*)(ar + kk * 32 + q * 8);
        }
#pragma unroll
        for (int nf = 0; nf < 9; nf++) {
            const f16* brow = wn_sh + (nf * 16 + r16) * 136 + q * 8;
#pragma unroll
            for (int kk = 0; kk < 4; kk++) {
                f16x8 bb = *(const f16x8*)(brow + kk * 32);
                acc[nf] = __builtin_amdgcn_mfma_f32_16x16x32_f16(a[kk], bb, acc[nf], 0, 0, 0);
            }
        }
    }

#pragma unroll
    for (int nf = 0; nf < 9; nf++) {
        int col = nf * 16 + r16;
        float bias = 0.f;
        if (col < 129)       bias = note_b[col];
        else if (col == 129) bias = dur_b[0];
#pragma unroll
        for (int r = 0; r < 4; r++) {
            int rowbt = bt0 + q * 4 + r;
            int t = t0 + q * 4 + r;
            float v = (t < len) ? (acc[nf][r] + bias) : 0.f;
            if (col < 129)
                out[(size_t)rowbt * P_ + col] = v;
            else if (col == 129)
                out[DUR_BASE + rowbt] = v;
        }
    }
}

// ---------------------------------------------------------------------------
extern "C" void kernel_launch(void* const* d_in, const int* in_sizes, int n_in,
                              void* d_out, int out_size, void* d_ws, size_t ws_size,
                              hipStream_t stream) {
    const float* x       = (const float*)d_in[0];
    const int*   lengths = (const int*)d_in[1];
    const float* W_ih    = (const float*)d_in[2];
    const float* W_hh    = (const float*)d_in[3];
    const float* note_W  = (const float*)d_in[4];
    const float* note_b  = (const float*)d_in[5];
    const float* dur_W   = (const float*)d_in[6];
    const float* dur_b   = (const float*)d_in[7];
    float* out = (float*)d_out;
    f16* Wn = (f16*)d_ws;

    prep_k<<<72, 256, 0, stream>>>(note_W, dur_W, Wn);
    lstm4_k<<<B_, 256, 0, stream>>>(x, lengths, W_ih, W_hh, out);
    proj_k<<<(B_ * T_) / 64, 256, 0, stream>>>(lengths, Wn, note_b, dur_b, out);
}